// Round 12
// baseline (1543.636 us; speedup 1.0000x reference)
//
#include <hip/hip_runtime.h>
#include <stdint.h>

#define N_TOK 4096
#define DIM_IN 512
#define NH 12
#define HD 64
#define CDIM 768   // NH*HD

using f32x4  = __attribute__((ext_vector_type(4))) float;
using f32x16 = __attribute__((ext_vector_type(16))) float;
using bf16x8 = __attribute__((ext_vector_type(8))) short;

static __device__ __forceinline__ unsigned short f2bf(float f){
    union { float f; unsigned int u; } v; v.f = f;
    unsigned int r = v.u + 0x7fffu + ((v.u >> 16) & 1u);
    return (unsigned short)(r >> 16);
}

// ---------------------------------------------------------------------------
// proj r12: both projections in ONE launch (blockIdx.z selects Wq/Wk) with
// the r11-verified register prefetch of the next d0-tile.
// ---------------------------------------------------------------------------
__global__ __launch_bounds__(256) void proj_kernel(
    const float* __restrict__ g,
    const float* __restrict__ Wq, const float* __restrict__ Wk,
    const float* __restrict__ Bq, const float* __restrict__ Bk,
    const float* __restrict__ betas,
    unsigned short* __restrict__ Qb, unsigned short* __restrict__ Kh)
{
    const int z = blockIdx.z;
    const float* W = z ? Wk : Wq;
    const float* B = z ? Bk : Bq;
    const float* scale = z ? nullptr : betas;
    unsigned short* out = z ? Kh : Qb;

    __shared__ float at[16][68];
    __shared__ float bt[16][68];
    const int n0 = blockIdx.x * 64, c0 = blockIdx.y * 64;
    const int t  = threadIdx.x;
    const int tx = t & 15, ty = t >> 4;
    const int lr = t >> 2, lk = (t & 3) * 4;
    float acc[4][4] = {};
    f32x4 pg = *(const f32x4*)&g[(size_t)(n0 + lr) * DIM_IN + lk];
    f32x4 pw = *(const f32x4*)&W[(size_t)(c0 + lr) * DIM_IN + lk];
    for (int d0 = 0; d0 < DIM_IN; d0 += 16){
        __syncthreads();
        at[lk+0][lr] = pg[0]; at[lk+1][lr] = pg[1]; at[lk+2][lr] = pg[2]; at[lk+3][lr] = pg[3];
        bt[lk+0][lr] = pw[0]; bt[lk+1][lr] = pw[1]; bt[lk+2][lr] = pw[2]; bt[lk+3][lr] = pw[3];
        __syncthreads();
        {
            const int dn = (d0 + 16 < DIM_IN) ? d0 + 16 : 0;   // clamped dummy
            pg = *(const f32x4*)&g[(size_t)(n0 + lr) * DIM_IN + dn + lk];
            pw = *(const f32x4*)&W[(size_t)(c0 + lr) * DIM_IN + dn + lk];
        }
        #pragma unroll
        for (int kk = 0; kk < 16; kk++){
            f32x4 av = *(const f32x4*)&at[kk][ty*4];
            f32x4 bv = *(const f32x4*)&bt[kk][tx*4];
            #pragma unroll
            for (int i = 0; i < 4; i++)
                #pragma unroll
                for (int j = 0; j < 4; j++)
                    acc[i][j] += av[i] * bv[j];
        }
    }
    #pragma unroll
    for (int i = 0; i < 4; i++){
        const int n = n0 + ty*4 + i;
        #pragma unroll
        for (int j = 0; j < 4; j++){
            const int c = c0 + tx*4 + j;
            float v = acc[i][j] + B[c];
            if (scale) v *= scale[c >> 6];
            out[(size_t)n * CDIM + c] = f2bf(v);
        }
    }
}

// ---------------------------------------------------------------------------
// forward r12 EXPERIMENT: global_load_lds direct staging.
//  - kbuf flat [32][768] (no pad).  Dest must be linear in lane (m104), so
//    the bank swizzle is applied on the SOURCE address (m173 pattern):
//    LDS[row][cc] = Kh[row][cc ^ ((row&7)<<3)]; reads XOR the same term.
//    Bank spread is equivalent to the old +8-pad layout by construction.
//  - pk[12] (48 regs) and the 12 ds_write/chunk are GONE; demand ~130.
//  - __launch_bounds__(256,3) + grid.y=12 (768 blocks = 3/CU): TLP covers
//    the single-buffer stage wait (m97 model).  Chunk-strided loop so any
//    grid.y divides the 128 chunks (l_ws accumulation is order-free).
// Falsifier: spill (FETCH balloon) or exposed stage -> revert to r10 fwd.
// ---------------------------------------------------------------------------
#define NCH 128   // 4096 / 32

__global__ __launch_bounds__(256, 3) void fwd_kernel(
    const unsigned short* __restrict__ Qb, const unsigned short* __restrict__ Kh,
    const float* __restrict__ adj, const float* __restrict__ HwG,
    float* __restrict__ l_ws)
{
    __shared__ unsigned short kbufF[32 * 768];   // 49152 B
    __shared__ float hw[NH][12];
    const int t = threadIdx.x;
    if (t < NH * 12) hw[t / 12][t % 12] = HwG[t];
    const int lane = t & 63, wave = t >> 6;
    const int quad = lane >> 4, col = lane & 15;
    const int qt0 = blockIdx.x * 64 + wave * 16;
    const unsigned short* qrow = &Qb[(size_t)(qt0 + col) * CDIM + quad*8];
    const int swr = (col & 7) << 3;   // read-side XOR (row&7 == col&7)

    f32x4 l4[4][3];
    #pragma unroll
    for (int r = 0; r < 4; r++)
        #pragma unroll
        for (int j = 0; j < 3; j++)
            l4[r][j] = (f32x4){0.f,0.f,0.f,0.f};

    for (int ci = blockIdx.y; ci < NCH; ci += gridDim.y){
        const int kc = ci * 32;
        __syncthreads();   // kbuf free (previous chunk fully consumed)
        #pragma unroll
        for (int i = 0; i < 12; i++){
            const int idx = t + 256 * i;
            const int row = idx / 96, cc = (idx % 96) * 8;
            const unsigned short* src =
                &Kh[(size_t)(kc + row) * CDIM + (cc ^ ((row & 7) << 3))];
            __builtin_amdgcn_global_load_lds(
                (const __attribute__((address_space(1))) unsigned int*)src,
                (__attribute__((address_space(3))) unsigned int*)&kbufF[idx * 8],
                16, 0, 0);
        }
        __syncthreads();   // vmcnt drained: kbuf ready for all waves

        #pragma unroll
        for (int sub = 0; sub < 2; sub++){
            const int k0 = kc + sub * 16;
            float av[4];
            #pragma unroll
            for (int r = 0; r < 4; r++)
                av[r] = adj[(size_t)(qt0 + quad*4 + r) * N_TOK + k0 + col];

            const unsigned short* qp = qrow;
            asm volatile("" : "+v"(qp));
            const unsigned short* kp = &kbufF[(sub*16 + col) * 768];

            f32x4 tv[4][3];
            #pragma unroll
            for (int r = 0; r < 4; r++)
                #pragma unroll
                for (int j = 0; j < 3; j++)
                    tv[r][j] = (f32x4){0.f,0.f,0.f,0.f};
            #pragma unroll
            for (int h = 0; h < NH; h++){
                bf16x8 a0 = *(const bf16x8*)&qp[h*HD];
                bf16x8 a1 = *(const bf16x8*)&qp[h*HD + 32];
                bf16x8 b0 = *(const bf16x8*)&kp[(h*HD + quad*8) ^ swr];
                bf16x8 b1 = *(const bf16x8*)&kp[(h*HD + 32 + quad*8) ^ swr];
                f32x4 s = {0.f,0.f,0.f,0.f};
                s = __builtin_amdgcn_mfma_f32_16x16x32_bf16(a0, b0, s, 0, 0, 0);
                s = __builtin_amdgcn_mfma_f32_16x16x32_bf16(a1, b1, s, 0, 0, 0);
                f32x4 w0 = *(const f32x4*)&hw[h][0];
                f32x4 w1 = *(const f32x4*)&hw[h][4];
                f32x4 w2 = *(const f32x4*)&hw[h][8];
                #pragma unroll
                for (int r = 0; r < 4; r++){
                    tv[r][0] += s[r] * w0;
                    tv[r][1] += s[r] * w1;
                    tv[r][2] += s[r] * w2;
                }
            }
            #pragma unroll
            for (int r = 0; r < 4; r++){
                #pragma unroll
                for (int j = 0; j < 3; j++){
                    #pragma unroll
                    for (int c = 0; c < 4; c++){
                        const float mm = tv[r][j][c] * av[r];   // matches T*adj
                        if (mm != 0.f) l4[r][j][c] += __expf(mm);
                    }
                }
            }
        }
    }
    #pragma unroll
    for (int r = 0; r < 4; r++)
        #pragma unroll
        for (int j = 0; j < 3; j++)
            #pragma unroll
            for (int c = 0; c < 4; c++){
                float v = l4[r][j][c];
                v += __shfl_xor(v, 1, 16);
                v += __shfl_xor(v, 2, 16);
                v += __shfl_xor(v, 4, 16);
                v += __shfl_xor(v, 8, 16);
                if (col == j*4 + c)
                    atomicAdd(&l_ws[(size_t)(qt0 + quad*4 + r) * NH + (j*4 + c)], v);
            }
}

// ---------------------------------------------------------------------------
// lse + energy
// ---------------------------------------------------------------------------
__global__ __launch_bounds__(256) void lse_energy_kernel(
    const float* __restrict__ l_ws, float* __restrict__ lse_ws,
    const float* __restrict__ betas, float* __restrict__ energy)
{
    const int t = threadIdx.x;
    const int i = blockIdx.x * 256 + t;
    const float l = l_ws[i];
    float lse, ep;
    if (l > 0.f){ lse = logf(l); ep = -(1.f / betas[i % NH]) * lse; }
    else        { lse = -1e30f; ep = 0.f; }
    lse_ws[i] = lse;
    __shared__ float red[256];
    red[t] = ep;
    __syncthreads();
    for (int s = 128; s > 0; s >>= 1){
        if (t < s) red[t] += red[t + s];
        __syncthreads();
    }
    if (t == 0) atomicAdd(energy, red[0]);
}

// ---------------------------------------------------------------------------
// backward: r11-VERBATIM (FROZEN at its structural floor, 477us/dispatch).
// Constraint ledger: 2 waves/EU -> 256-reg cap, demand ~170; r6 (global
// operands), r7 (colmatT), r8 (early prefetch) all regressed; 2-block/CU
// variants hit the accumulator wall (rows*768*4B/threads).  FETCH ~98MB is
// near-ideal (adj read-once dominates).
// ---------------------------------------------------------------------------
#define CBS 776   // colbuf ushort stride

template<int MODE>
__global__ __attribute__((amdgpu_flat_work_group_size(512, 512), amdgpu_waves_per_eu(2, 2)))
void bwd_kernel(
    const unsigned short* __restrict__ rowmat, const unsigned short* __restrict__ colmat,
    const float* __restrict__ adj, const float* __restrict__ HwG,
    const float* __restrict__ lse_ws, const float* __restrict__ betas,
    float* __restrict__ out_part, int seg_len)
{
    __shared__ unsigned short colbuf[64][CBS];     // 99328 B
    __shared__ unsigned short dsbuf[NH][32][64];   // 49152 B
    __shared__ float adjbuf[32][68];               //  8704 B
    __shared__ float lsebuf[64 * NH];              //  3072 B (mode 1 only)
    __shared__ float rowlse[32 * NH];              //  1536 B (mode 0 only)
    __shared__ float invbuf[NH];                   //    48 B
    __shared__ float hw[NH][12];                   //   576 B
    const int t = threadIdx.x;
    if (t < NH * 12) hw[t / 12][t % 12] = HwG[t];
    if (t < NH) invbuf[t] = 1.f / betas[t];
    const int lane = t & 63, wave = t >> 6;
    const int quad = lane >> 4, col = lane & 15;
    const int rsub = wave >> 2, csub = wave & 3;
    const int n0 = csub * 16;
    const int rt0 = blockIdx.x * 32;
    const int rbase = rt0 + rsub * 16;       // this wave's 16 rows (phase A)
    const int cstart = blockIdx.y * seg_len;
    const int tA = n0 + col;

    if (MODE == 0 && t < 96)
        *(f32x4*)&rowlse[t*4] = *(const f32x4*)&lse_ws[(size_t)rt0 * NH + t*4];

    // A-fragment source row for this lane (16 B aligned vector loads)
    const unsigned short* rowp = &rowmat[(size_t)(rbase + col) * CDIM + quad*8];

    const int adj_m  = t >> 4, adj_nc = (t & 15) * 4;   // mode 0
    const int adj_qr = t >> 3, adj_kc = (t & 7) * 4;    // mode 1

    // ---- initial prefetch (chunk 0) ----
    bf16x8 pcol[12];
    f32x4  padj;
    f32x4  plse = {0.f,0.f,0.f,0.f};
    {
        const int cb = cstart;
        #pragma unroll
        for (int i = 0; i < 12; i++){
            const int idx = t + 512 * i;
            const int row = idx / 96, cc = (idx % 96) * 8;
            pcol[i] = *(const bf16x8*)&colmat[(size_t)(cb + row) * CDIM + cc];
        }
        if (MODE == 0) padj = *(const f32x4*)&adj[(size_t)(rt0 + adj_m) * N_TOK + cb + adj_nc];
        else           padj = *(const f32x4*)&adj[(size_t)(cb + adj_qr) * N_TOK + rt0 + adj_kc];
        if (MODE == 1 && t < 192)
            plse = *(const f32x4*)&lse_ws[(size_t)cb * NH + t*4];
    }

    f32x16 accB32[3];
    #pragma unroll
    for (int gg = 0; gg < 3; gg++)
        #pragma unroll
        for (int q = 0; q < 16; q++) accB32[gg][q] = 0.f;

    for (int cb = cstart; cb < cstart + seg_len; cb += 64){
        __syncthreads();
        // ---- write prefetched chunk into LDS ----
        #pragma unroll
        for (int i = 0; i < 12; i++){
            const int idx = t + 512 * i;
            const int row = idx / 96, cc = (idx % 96) * 8;
            // swizzled store: logical channel c lives at c ^ ((row>>3 & 3)<<3)
            *(bf16x8*)&colbuf[row][cc ^ (((row >> 3) & 3) << 3)] = pcol[i];
        }
        if (MODE == 0){
            adjbuf[adj_m][adj_nc+0] = padj[0]; adjbuf[adj_m][adj_nc+1] = padj[1];
            adjbuf[adj_m][adj_nc+2] = padj[2]; adjbuf[adj_m][adj_nc+3] = padj[3];
        } else {
            adjbuf[adj_kc+0][adj_qr] = padj[0]; adjbuf[adj_kc+1][adj_qr] = padj[1];
            adjbuf[adj_kc+2][adj_qr] = padj[2]; adjbuf[adj_kc+3][adj_qr] = padj[3];
        }
        if (MODE == 1 && t < 192)
            *(f32x4*)&lsebuf[t*4] = plse;
        __syncthreads();

        // launder the A-row pointer so the per-h loads below cannot be
        // hoisted out of the cb loop (would recreate a 96-reg af array)
        const unsigned short* rp = rowp;
        asm volatile("" : "+v"(rp));

        // ---- phase A: this wave's 16 rows x 16 cols (csub subtile) ----
        {
            const int swzA = ((tA >> 3) & 3) << 3;
            f32x4 G[4][3];
            #pragma unroll
            for (int r = 0; r < 4; r++)
                #pragma unroll
                for (int j = 0; j < 3; j++)
                    G[r][j] = (f32x4){0.f,0.f,0.f,0.f};
            #pragma unroll
            for (int h = 0; h < NH; h++){
                bf16x8 a0 = *(const bf16x8*)&rp[h*HD];
                bf16x8 a1 = *(const bf16x8*)&rp[h*HD + 32];
                bf16x8 b0 = *(const bf16x8*)&colbuf[tA][(h*HD + quad*8) ^ swzA];
                bf16x8 b1 = *(const bf16x8*)&colbuf[tA][(h*HD + 32 + quad*8) ^ swzA];
                f32x4 s = {0.f,0.f,0.f,0.f};
                s = __builtin_amdgcn_mfma_f32_16x16x32_bf16(a0, b0, s, 0, 0, 0);
                s = __builtin_amdgcn_mfma_f32_16x16x32_bf16(a1, b1, s, 0, 0, 0);
                f32x4 w0 = *(const f32x4*)&hw[h][0];
                f32x4 w1 = *(const f32x4*)&hw[h][4];
                f32x4 w2 = *(const f32x4*)&hw[h][8];
                #pragma unroll
                for (int r = 0; r < 4; r++){
                    G[r][0] += s[r] * w0;
                    G[r][1] += s[r] * w1;
                    G[r][2] += s[r] * w2;
                }
            }
            // t-values -> gradient G = -(1/b')*P   (lse + 1/beta from LDS)
            #pragma unroll
            for (int r = 0; r < 4; r++){
                const float adjv = adjbuf[rsub*16 + quad*4 + r][tA];
                #pragma unroll
                for (int j = 0; j < 3; j++){
                    f32x4 lv;
                    if (MODE == 0) lv = *(const f32x4*)&rowlse[(rsub*16 + quad*4 + r) * NH + j*4];
                    else           lv = *(const f32x4*)&lsebuf[tA * NH + j*4];
                    #pragma unroll
                    for (int c = 0; c < 4; c++){
                        const float mm = G[r][j][c] * adjv;
                        const float p  = (mm != 0.f) ? __expf(mm - lv[c]) : 0.f;
                        G[r][j][c] = -invbuf[j*4 + c] * p;
                    }
                }
            }
            // dS = G @ Hw^T, bf16 into dsbuf (swizzled: kk' = kk ^ ((m&7)<<3))
            #pragma unroll
            for (int h = 0; h < NH; h++){
                f32x4 w0 = *(const f32x4*)&hw[h][0];
                f32x4 w1 = *(const f32x4*)&hw[h][4];
                f32x4 w2 = *(const f32x4*)&hw[h][8];
                #pragma unroll
                for (int r = 0; r < 4; r++){
                    f32x4 pr = G[r][0]*w0 + G[r][1]*w1 + G[r][2]*w2;
                    const float d = pr[0] + pr[1] + pr[2] + pr[3];
                    const int m = rsub*16 + quad*4 + r;
                    dsbuf[h][m][tA ^ ((m & 7) << 3)] = f2bf(d);
                }
            }
        }

        // ---- issue prefetch of chunk t+1 (G dead; r5/r9 placement) ----
        {
            const int nxt = cb + 64;
            const int cbn = (nxt < cstart + seg_len) ? nxt : cstart;  // clamp (discarded)
            #pragma unroll
            for (int i = 0; i < 12; i++){
                const int idx = t + 512 * i;
                const int row = idx / 96, cc = (idx % 96) * 8;
                pcol[i] = *(const bf16x8*)&colmat[(size_t)(cbn + row) * CDIM + cc];
            }
            if (MODE == 0) padj = *(const f32x4*)&adj[(size_t)(rt0 + adj_m) * N_TOK + cbn + adj_nc];
            else           padj = *(const f32x4*)&adj[(size_t)(cbn + adj_qr) * N_TOK + rt0 + adj_kc];
            if (MODE == 1 && t < 192)
                plse = *(const f32x4*)&lse_ws[(size_t)cbn * NH + t*4];
        }
        __syncthreads();

        // ---- phase B (32x32x16): dRow[m][z] += sum_kk dS[m][kk]*colmat[kk][z]
        {
            const int mB = lane & 31;
            const int halfB = lane >> 5;
            #pragma unroll
            for (int gg = 0; gg < 3; gg++){
                const int gidx = wave + gg*8;
                const int h = gidx >> 1, cg = gidx & 1;
                const int chL = h*HD + cg*32 + mB;     // logical chan for B
                f32x16 acc = accB32[gg];
                #pragma unroll
                for (int k0 = 0; k0 < 64; k0 += 16){
                    const int kbase = k0 + halfB*8;
                    // A: dS[mB][kbase .. +8]  (swizzle-compatible contiguous)
                    bf16x8 a = *(const bf16x8*)&dsbuf[h][mB][kbase ^ ((mB & 7) << 3)];
                    // B: colmat[kbase+jj][chL], jj=0..7 ; swizzle const over jj
                    const int sw = ((kbase >> 3) & 3) << 3;
                    const unsigned short* bp = &colbuf[kbase][chL ^ sw];
                    bf16x8 b;
                    #pragma unroll
                    for (int jj = 0; jj < 8; jj++)
                        b[jj] = (short)bp[jj * CBS];
                    acc = __builtin_amdgcn_mfma_f32_32x32x16_bf16(a, b, acc, 0, 0, 0);
                }
                accB32[gg] = acc;
            }
        }
    }
    // ---- write dRow partials (32x32 D layout, r5-verified) ----
    float* outp = out_part + (size_t)blockIdx.y * N_TOK * CDIM;
    #pragma unroll
    for (int gg = 0; gg < 3; gg++){
        const int gidx = wave + gg*8;
        const int h = gidx >> 1, cg = gidx & 1;
        #pragma unroll
        for (int q = 0; q < 16; q++){
            const int i = (q & 3) + 8*(q >> 2) + 4*(lane >> 5);
            outp[(size_t)(rt0 + i) * CDIM + h*HD + cg*32 + (lane & 31)] = accB32[gg][q];
        }
    }
}

// ---------------------------------------------------------------------------
// final r11-verbatim: templated NSEG + register prefetch.
// ---------------------------------------------------------------------------
template<int NSEG>
__global__ __launch_bounds__(256) void final_dg_kernel(
    const float* __restrict__ dQbp, const float* __restrict__ dKhp,
    const float* __restrict__ Wq, const float* __restrict__ Wk,
    const float* __restrict__ betas, float* __restrict__ dg)
{
    __shared__ float at[16][68];
    __shared__ float bt[16][68];
    const int n0 = blockIdx.x * 64, d0 = blockIdx.y * 64;
    const int t  = threadIdx.x;
    const int tx = t & 15, ty = t >> 4;
    const int lr = t >> 2, lk = (t & 3) * 4;
    const int wk = t >> 4, wd = (t & 15) * 4;   // W staging mapping
    float acc[4][4] = {};

    f32x4 la[NSEG];
    f32x4 lw;
    auto issue = [&](int it){
        const int src = it / 48;
        const int c0i = (it % 48) * 16;
        const float* P = src ? dKhp : dQbp;
        const float* W = src ? Wk  : Wq;
        #pragma unroll
        for (int s = 0; s < NSEG; s++)
            la[s] = *(const f32x4*)&P[((size_t)s * N_TOK + n0 + lr) * CDIM + c0i + lk];
        lw = *(const f32x4*)&W[(size_t)(c0i + wk) * DIM_IN + d0 + wd];
    };
    issue(0);

    for (int it = 0; it < 96; it++){
        const int src = it / 48;
        const int c0i = (it % 48) * 16;
        __syncthreads();
        f32x4 a = la[0];
        #pragma unroll
        for (int s = 1; s < NSEG; s++) a += la[s];
        if (src == 0) a *= betas[(c0i + lk) >> 6];
        at[lk+0][lr] = a[0]; at[lk+1][lr] = a[1]; at[lk+2][lr] = a[2]; at[lk+3][lr] = a[3];
        bt[wk][wd+0] = lw[0]; bt[wk][wd+1] = lw[1]; bt[wk][wd+2] = lw[2]; bt[wk][wd+3] = lw[3];
        __syncthreads();
        issue(it + 1 < 96 ? it + 1 : 0);   // clamped dummy on last iter
        #pragma unroll
        for (int kk = 0; kk < 16; kk++){
            f32x4 av = *(const f32x4*)&at[kk][ty*4];
            f32x4 bv = *(const f32x4*)&bt[kk][tx*4];
            #pragma unroll
            for (int i = 0; i < 4; i++)
                #pragma unroll
                for (int j = 0; j < 4; j++)
                    acc[i][j] += av[i] * bv[j];
        }
    }
    #pragma unroll
    for (int i = 0; i < 4; i++)
        #pragma unroll
        for (int j = 0; j < 4; j++)
            dg[(size_t)(n0 + ty*4 + i) * DIM_IN + d0 + tx*4 + j] = acc[i][j];
}

// ---------------------------------------------------------------------------
extern "C" void kernel_launch(void* const* d_in, const int* in_sizes, int n_in,
                              void* d_out, int out_size, void* d_ws, size_t ws_size,
                              hipStream_t stream)
{
    const float* g     = (const float*)d_in[0];
    const float* adj   = (const float*)d_in[1];
    const float* Wk    = (const float*)d_in[2];
    const float* Wq    = (const float*)d_in[3];
    const float* Hw    = (const float*)d_in[4];
    const float* Bk    = (const float*)d_in[5];
    const float* Bq    = (const float*)d_in[6];
    const float* betas = (const float*)d_in[7];
    float* out = (float*)d_out;

    char* ws = (char*)d_ws;
    const size_t szQb   = (size_t)N_TOK * CDIM * sizeof(unsigned short); // 6291456
    const size_t szL    = (size_t)N_TOK * NH * sizeof(float);            // 196608
    const size_t szPart = (size_t)N_TOK * CDIM * sizeof(float);          // 12582912

    unsigned short* Qb = (unsigned short*)(ws);
    unsigned short* Kh = (unsigned short*)(ws + szQb);
    float* l_ws   = (float*)(ws + 2*szQb);
    float* lse_ws = (float*)(ws + 2*szQb + szL);
    char*  parts  = ws + 2*szQb + 2*szL;
    const size_t base = 2*szQb + 2*szL;

    int KS = 1;
    if      (ws_size >= base + 8*szPart) KS = 4;
    else if (ws_size >= base + 4*szPart) KS = 2;
    float* dQbp = (float*)parts;
    float* dKhp = (float*)(parts + (size_t)KS * szPart);

    hipMemsetAsync(l_ws, 0, szL, stream);
    hipMemsetAsync(d_out, 0, sizeof(float), stream);

    proj_kernel<<<dim3(64, 12, 2), 256, 0, stream>>>(g, Wq, Wk, Bq, Bk, betas, Qb, Kh);
    fwd_kernel<<<dim3(64, 12), 256, 0, stream>>>(Qb, Kh, adj, Hw, l_ws);
    lse_energy_kernel<<<dim3(192), 256, 0, stream>>>(l_ws, lse_ws, betas, out);
    bwd_kernel<0><<<dim3(128, KS), 512, 0, stream>>>(Qb, Kh, adj, Hw, lse_ws, betas,
                                                     dQbp, N_TOK / KS);
    bwd_kernel<1><<<dim3(128, KS), 512, 0, stream>>>(Kh, Qb, adj, Hw, lse_ws, betas,
                                                     dKhp, N_TOK / KS);
    if (KS == 4)
        final_dg_kernel<4><<<dim3(64, 8), 256, 0, stream>>>(dQbp, dKhp, Wq, Wk, betas, out + 1);
    else if (KS == 2)
        final_dg_kernel<2><<<dim3(64, 8), 256, 0, stream>>>(dQbp, dKhp, Wq, Wk, betas, out + 1);
    else
        final_dg_kernel<1><<<dim3(64, 8), 256, 0, stream>>>(dQbp, dKhp, Wq, Wk, betas, out + 1);
}

// Round 13
// 1379.233 us; speedup vs baseline: 1.1192x; 1.1192x over previous
//
#include <hip/hip_runtime.h>
#include <stdint.h>

#define N_TOK 4096
#define DIM_IN 512
#define NH 12
#define HD 64
#define CDIM 768   // NH*HD

using f32x4  = __attribute__((ext_vector_type(4))) float;
using f32x16 = __attribute__((ext_vector_type(16))) float;
using bf16x8 = __attribute__((ext_vector_type(8))) short;

static __device__ __forceinline__ unsigned short f2bf(float f){
    union { float f; unsigned int u; } v; v.f = f;
    unsigned int r = v.u + 0x7fffu + ((v.u >> 16) & 1u);
    return (unsigned short)(r >> 16);
}

// ---------------------------------------------------------------------------
// proj: both projections in ONE launch (blockIdx.z selects Wq/Wk); inner code
// identical to the r11-verified version (register prefetch of next d0-tile).
// ---------------------------------------------------------------------------
__global__ __launch_bounds__(256) void proj_kernel(
    const float* __restrict__ g,
    const float* __restrict__ Wq, const float* __restrict__ Wk,
    const float* __restrict__ Bq, const float* __restrict__ Bk,
    const float* __restrict__ betas,
    unsigned short* __restrict__ Qb, unsigned short* __restrict__ Kh)
{
    const int z = blockIdx.z;
    const float* W = z ? Wk : Wq;
    const float* B = z ? Bk : Bq;
    const float* scale = z ? nullptr : betas;
    unsigned short* out = z ? Kh : Qb;

    __shared__ float at[16][68];
    __shared__ float bt[16][68];
    const int n0 = blockIdx.x * 64, c0 = blockIdx.y * 64;
    const int t  = threadIdx.x;
    const int tx = t & 15, ty = t >> 4;
    const int lr = t >> 2, lk = (t & 3) * 4;
    float acc[4][4] = {};
    f32x4 pg = *(const f32x4*)&g[(size_t)(n0 + lr) * DIM_IN + lk];
    f32x4 pw = *(const f32x4*)&W[(size_t)(c0 + lr) * DIM_IN + lk];
    for (int d0 = 0; d0 < DIM_IN; d0 += 16){
        __syncthreads();
        at[lk+0][lr] = pg[0]; at[lk+1][lr] = pg[1]; at[lk+2][lr] = pg[2]; at[lk+3][lr] = pg[3];
        bt[lk+0][lr] = pw[0]; bt[lk+1][lr] = pw[1]; bt[lk+2][lr] = pw[2]; bt[lk+3][lr] = pw[3];
        __syncthreads();
        {
            const int dn = (d0 + 16 < DIM_IN) ? d0 + 16 : 0;   // clamped dummy
            pg = *(const f32x4*)&g[(size_t)(n0 + lr) * DIM_IN + dn + lk];
            pw = *(const f32x4*)&W[(size_t)(c0 + lr) * DIM_IN + dn + lk];
        }
        #pragma unroll
        for (int kk = 0; kk < 16; kk++){
            f32x4 av = *(const f32x4*)&at[kk][ty*4];
            f32x4 bv = *(const f32x4*)&bt[kk][tx*4];
            #pragma unroll
            for (int i = 0; i < 4; i++)
                #pragma unroll
                for (int j = 0; j < 4; j++)
                    acc[i][j] += av[i] * bv[j];
        }
    }
    #pragma unroll
    for (int i = 0; i < 4; i++){
        const int n = n0 + ty*4 + i;
        #pragma unroll
        for (int j = 0; j < 4; j++){
            const int c = c0 + tx*4 + j;
            float v = acc[i][j] + B[c];
            if (scale) v *= scale[c >> 6];
            out[(size_t)n * CDIM + c] = f2bf(v);
        }
    }
}

// ---------------------------------------------------------------------------
// forward (r11-verbatim, verified): kbuf staging + pk[12] register prefetch
// issued after the post-staging barrier; af reloaded per sub via laundered
// pointer so demand stays ~185 <= 256 with pk live through compute.
// r12's global_load_lds single-buffer variant regressed (+135us: stage wait
// exposed; the register double-buffer was what hid it) -- reverted.
// ---------------------------------------------------------------------------
#define TKF 32
#define KBS 776   // ushort stride: 1552 B (16B aligned, 2-way-bank only)

__global__ __launch_bounds__(256, 2) void fwd_kernel(
    const unsigned short* __restrict__ Qb, const unsigned short* __restrict__ Kh,
    const float* __restrict__ adj, const float* __restrict__ HwG,
    float* __restrict__ l_ws, int seg_len)
{
    __shared__ unsigned short kbuf[TKF][KBS];
    __shared__ float hw[NH][12];
    const int t = threadIdx.x;
    if (t < NH * 12) hw[t / 12][t % 12] = HwG[t];
    const int lane = t & 63, wave = t >> 6;
    const int quad = lane >> 4, col = lane & 15;
    const int qt0 = blockIdx.x * 64 + wave * 16;
    const int kstart = blockIdx.y * seg_len;
    const unsigned short* qrow = &Qb[(size_t)(qt0 + col) * CDIM + quad*8];

    f32x4 l4[4][3];
    #pragma unroll
    for (int r = 0; r < 4; r++)
        #pragma unroll
        for (int j = 0; j < 3; j++)
            l4[r][j] = (f32x4){0.f,0.f,0.f,0.f};

    // ---- prologue prefetch (chunk 0) ----
    bf16x8 pk[12];
    #pragma unroll
    for (int i = 0; i < 12; i++){
        const int idx = t + 256 * i;
        const int row = idx / 96, cc = (idx % 96) * 8;
        pk[i] = *(const bf16x8*)&Kh[(size_t)(kstart + row) * CDIM + cc];
    }

    for (int kc = kstart; kc < kstart + seg_len; kc += TKF){
        __syncthreads();
        #pragma unroll
        for (int i = 0; i < 12; i++){
            const int idx = t + 256 * i;
            const int row = idx / 96, cc = (idx % 96) * 8;
            *(bf16x8*)&kbuf[row][cc] = pk[i];
        }
        __syncthreads();

        // issue next chunk's loads: covered by the full 2-sub compute below
        {
            const int nxt = kc + TKF;
            const int kcn = (nxt < kstart + seg_len) ? nxt : kstart;  // clamped dummy
            #pragma unroll
            for (int i = 0; i < 12; i++){
                const int idx = t + 256 * i;
                const int row = idx / 96, cc = (idx % 96) * 8;
                pk[i] = *(const bf16x8*)&Kh[(size_t)(kcn + row) * CDIM + cc];
            }
        }

        #pragma unroll
        for (int sub = 0; sub < 2; sub++){
            const int k0 = kc + sub * 16;
            float av[4];
            #pragma unroll
            for (int r = 0; r < 4; r++)
                av[r] = adj[(size_t)(qt0 + quad*4 + r) * N_TOK + k0 + col];

            const unsigned short* qp = qrow;
            asm volatile("" : "+v"(qp));

            f32x4 tv[4][3];
            #pragma unroll
            for (int r = 0; r < 4; r++)
                #pragma unroll
                for (int j = 0; j < 3; j++)
                    tv[r][j] = (f32x4){0.f,0.f,0.f,0.f};
            #pragma unroll
            for (int h = 0; h < NH; h++){
                bf16x8 a0 = *(const bf16x8*)&qp[h*HD];
                bf16x8 a1 = *(const bf16x8*)&qp[h*HD + 32];
                bf16x8 b0 = *(const bf16x8*)&kbuf[sub*16 + col][h*HD + quad*8];
                bf16x8 b1 = *(const bf16x8*)&kbuf[sub*16 + col][h*HD + 32 + quad*8];
                f32x4 s = {0.f,0.f,0.f,0.f};
                s = __builtin_amdgcn_mfma_f32_16x16x32_bf16(a0, b0, s, 0, 0, 0);
                s = __builtin_amdgcn_mfma_f32_16x16x32_bf16(a1, b1, s, 0, 0, 0);
                f32x4 w0 = *(const f32x4*)&hw[h][0];
                f32x4 w1 = *(const f32x4*)&hw[h][4];
                f32x4 w2 = *(const f32x4*)&hw[h][8];
                #pragma unroll
                for (int r = 0; r < 4; r++){
                    tv[r][0] += s[r] * w0;
                    tv[r][1] += s[r] * w1;
                    tv[r][2] += s[r] * w2;
                }
            }
            #pragma unroll
            for (int r = 0; r < 4; r++){
                #pragma unroll
                for (int j = 0; j < 3; j++){
                    #pragma unroll
                    for (int c = 0; c < 4; c++){
                        const float mm = tv[r][j][c] * av[r];   // matches T*adj
                        if (mm != 0.f) l4[r][j][c] += __expf(mm);
                    }
                }
            }
        }
    }
    #pragma unroll
    for (int r = 0; r < 4; r++)
        #pragma unroll
        for (int j = 0; j < 3; j++)
            #pragma unroll
            for (int c = 0; c < 4; c++){
                float v = l4[r][j][c];
                v += __shfl_xor(v, 1, 16);
                v += __shfl_xor(v, 2, 16);
                v += __shfl_xor(v, 4, 16);
                v += __shfl_xor(v, 8, 16);
                if (col == j*4 + c)
                    atomicAdd(&l_ws[(size_t)(qt0 + quad*4 + r) * NH + (j*4 + c)], v);
            }
}

// ---------------------------------------------------------------------------
// lse + energy
// ---------------------------------------------------------------------------
__global__ __launch_bounds__(256) void lse_energy_kernel(
    const float* __restrict__ l_ws, float* __restrict__ lse_ws,
    const float* __restrict__ betas, float* __restrict__ energy)
{
    const int t = threadIdx.x;
    const int i = blockIdx.x * 256 + t;
    const float l = l_ws[i];
    float lse, ep;
    if (l > 0.f){ lse = logf(l); ep = -(1.f / betas[i % NH]) * lse; }
    else        { lse = -1e30f; ep = 0.f; }
    lse_ws[i] = lse;
    __shared__ float red[256];
    red[t] = ep;
    __syncthreads();
    for (int s = 128; s > 0; s >>= 1){
        if (t < s) red[t] += red[t + s];
        __syncthreads();
    }
    if (t == 0) atomicAdd(energy, red[0]);
}

// ---------------------------------------------------------------------------
// backward: r11-VERBATIM (FROZEN at its structural floor, ~477us/dispatch).
// Constraint ledger: 2 waves/EU -> 256-reg cap, demand ~170; r6 (global
// operands), r7 (colmatT), r8 (early prefetch), r12 (gload_lds fwd analog)
// all regressed.  FETCH ~98MB is near-ideal (adj read-once dominates).
// ---------------------------------------------------------------------------
#define CBS 776   // colbuf ushort stride

template<int MODE>
__global__ __attribute__((amdgpu_flat_work_group_size(512, 512), amdgpu_waves_per_eu(2, 2)))
void bwd_kernel(
    const unsigned short* __restrict__ rowmat, const unsigned short* __restrict__ colmat,
    const float* __restrict__ adj, const float* __restrict__ HwG,
    const float* __restrict__ lse_ws, const float* __restrict__ betas,
    float* __restrict__ out_part, int seg_len)
{
    __shared__ unsigned short colbuf[64][CBS];     // 99328 B
    __shared__ unsigned short dsbuf[NH][32][64];   // 49152 B
    __shared__ float adjbuf[32][68];               //  8704 B
    __shared__ float lsebuf[64 * NH];              //  3072 B (mode 1 only)
    __shared__ float rowlse[32 * NH];              //  1536 B (mode 0 only)
    __shared__ float invbuf[NH];                   //    48 B
    __shared__ float hw[NH][12];                   //   576 B
    const int t = threadIdx.x;
    if (t < NH * 12) hw[t / 12][t % 12] = HwG[t];
    if (t < NH) invbuf[t] = 1.f / betas[t];
    const int lane = t & 63, wave = t >> 6;
    const int quad = lane >> 4, col = lane & 15;
    const int rsub = wave >> 2, csub = wave & 3;
    const int n0 = csub * 16;
    const int rt0 = blockIdx.x * 32;
    const int rbase = rt0 + rsub * 16;       // this wave's 16 rows (phase A)
    const int cstart = blockIdx.y * seg_len;
    const int tA = n0 + col;

    if (MODE == 0 && t < 96)
        *(f32x4*)&rowlse[t*4] = *(const f32x4*)&lse_ws[(size_t)rt0 * NH + t*4];

    // A-fragment source row for this lane (16 B aligned vector loads)
    const unsigned short* rowp = &rowmat[(size_t)(rbase + col) * CDIM + quad*8];

    const int adj_m  = t >> 4, adj_nc = (t & 15) * 4;   // mode 0
    const int adj_qr = t >> 3, adj_kc = (t & 7) * 4;    // mode 1

    // ---- initial prefetch (chunk 0) ----
    bf16x8 pcol[12];
    f32x4  padj;
    f32x4  plse = {0.f,0.f,0.f,0.f};
    {
        const int cb = cstart;
        #pragma unroll
        for (int i = 0; i < 12; i++){
            const int idx = t + 512 * i;
            const int row = idx / 96, cc = (idx % 96) * 8;
            pcol[i] = *(const bf16x8*)&colmat[(size_t)(cb + row) * CDIM + cc];
        }
        if (MODE == 0) padj = *(const f32x4*)&adj[(size_t)(rt0 + adj_m) * N_TOK + cb + adj_nc];
        else           padj = *(const f32x4*)&adj[(size_t)(cb + adj_qr) * N_TOK + rt0 + adj_kc];
        if (MODE == 1 && t < 192)
            plse = *(const f32x4*)&lse_ws[(size_t)cb * NH + t*4];
    }

    f32x16 accB32[3];
    #pragma unroll
    for (int gg = 0; gg < 3; gg++)
        #pragma unroll
        for (int q = 0; q < 16; q++) accB32[gg][q] = 0.f;

    for (int cb = cstart; cb < cstart + seg_len; cb += 64){
        __syncthreads();
        // ---- write prefetched chunk into LDS ----
        #pragma unroll
        for (int i = 0; i < 12; i++){
            const int idx = t + 512 * i;
            const int row = idx / 96, cc = (idx % 96) * 8;
            // swizzled store: logical channel c lives at c ^ ((row>>3 & 3)<<3)
            *(bf16x8*)&colbuf[row][cc ^ (((row >> 3) & 3) << 3)] = pcol[i];
        }
        if (MODE == 0){
            adjbuf[adj_m][adj_nc+0] = padj[0]; adjbuf[adj_m][adj_nc+1] = padj[1];
            adjbuf[adj_m][adj_nc+2] = padj[2]; adjbuf[adj_m][adj_nc+3] = padj[3];
        } else {
            adjbuf[adj_kc+0][adj_qr] = padj[0]; adjbuf[adj_kc+1][adj_qr] = padj[1];
            adjbuf[adj_kc+2][adj_qr] = padj[2]; adjbuf[adj_kc+3][adj_qr] = padj[3];
        }
        if (MODE == 1 && t < 192)
            *(f32x4*)&lsebuf[t*4] = plse;
        __syncthreads();

        // launder the A-row pointer so the per-h loads below cannot be
        // hoisted out of the cb loop (would recreate a 96-reg af array)
        const unsigned short* rp = rowp;
        asm volatile("" : "+v"(rp));

        // ---- phase A: this wave's 16 rows x 16 cols (csub subtile) ----
        {
            const int swzA = ((tA >> 3) & 3) << 3;
            f32x4 G[4][3];
            #pragma unroll
            for (int r = 0; r < 4; r++)
                #pragma unroll
                for (int j = 0; j < 3; j++)
                    G[r][j] = (f32x4){0.f,0.f,0.f,0.f};
            #pragma unroll
            for (int h = 0; h < NH; h++){
                bf16x8 a0 = *(const bf16x8*)&rp[h*HD];
                bf16x8 a1 = *(const bf16x8*)&rp[h*HD + 32];
                bf16x8 b0 = *(const bf16x8*)&colbuf[tA][(h*HD + quad*8) ^ swzA];
                bf16x8 b1 = *(const bf16x8*)&colbuf[tA][(h*HD + 32 + quad*8) ^ swzA];
                f32x4 s = {0.f,0.f,0.f,0.f};
                s = __builtin_amdgcn_mfma_f32_16x16x32_bf16(a0, b0, s, 0, 0, 0);
                s = __builtin_amdgcn_mfma_f32_16x16x32_bf16(a1, b1, s, 0, 0, 0);
                f32x4 w0 = *(const f32x4*)&hw[h][0];
                f32x4 w1 = *(const f32x4*)&hw[h][4];
                f32x4 w2 = *(const f32x4*)&hw[h][8];
                #pragma unroll
                for (int r = 0; r < 4; r++){
                    G[r][0] += s[r] * w0;
                    G[r][1] += s[r] * w1;
                    G[r][2] += s[r] * w2;
                }
            }
            // t-values -> gradient G = -(1/b')*P   (lse + 1/beta from LDS)
            #pragma unroll
            for (int r = 0; r < 4; r++){
                const float adjv = adjbuf[rsub*16 + quad*4 + r][tA];
                #pragma unroll
                for (int j = 0; j < 3; j++){
                    f32x4 lv;
                    if (MODE == 0) lv = *(const f32x4*)&rowlse[(rsub*16 + quad*4 + r) * NH + j*4];
                    else           lv = *(const f32x4*)&lsebuf[tA * NH + j*4];
                    #pragma unroll
                    for (int c = 0; c < 4; c++){
                        const float mm = G[r][j][c] * adjv;
                        const float p  = (mm != 0.f) ? __expf(mm - lv[c]) : 0.f;
                        G[r][j][c] = -invbuf[j*4 + c] * p;
                    }
                }
            }
            // dS = G @ Hw^T, bf16 into dsbuf (swizzled: kk' = kk ^ ((m&7)<<3))
            #pragma unroll
            for (int h = 0; h < NH; h++){
                f32x4 w0 = *(const f32x4*)&hw[h][0];
                f32x4 w1 = *(const f32x4*)&hw[h][4];
                f32x4 w2 = *(const f32x4*)&hw[h][8];
                #pragma unroll
                for (int r = 0; r < 4; r++){
                    f32x4 pr = G[r][0]*w0 + G[r][1]*w1 + G[r][2]*w2;
                    const float d = pr[0] + pr[1] + pr[2] + pr[3];
                    const int m = rsub*16 + quad*4 + r;
                    dsbuf[h][m][tA ^ ((m & 7) << 3)] = f2bf(d);
                }
            }
        }

        // ---- issue prefetch of chunk t+1 (G dead; r5/r9 placement) ----
        {
            const int nxt = cb + 64;
            const int cbn = (nxt < cstart + seg_len) ? nxt : cstart;  // clamp (discarded)
            #pragma unroll
            for (int i = 0; i < 12; i++){
                const int idx = t + 512 * i;
                const int row = idx / 96, cc = (idx % 96) * 8;
                pcol[i] = *(const bf16x8*)&colmat[(size_t)(cbn + row) * CDIM + cc];
            }
            if (MODE == 0) padj = *(const f32x4*)&adj[(size_t)(rt0 + adj_m) * N_TOK + cbn + adj_nc];
            else           padj = *(const f32x4*)&adj[(size_t)(cbn + adj_qr) * N_TOK + rt0 + adj_kc];
            if (MODE == 1 && t < 192)
                plse = *(const f32x4*)&lse_ws[(size_t)cbn * NH + t*4];
        }
        __syncthreads();

        // ---- phase B (32x32x16): dRow[m][z] += sum_kk dS[m][kk]*colmat[kk][z]
        {
            const int mB = lane & 31;
            const int halfB = lane >> 5;
            #pragma unroll
            for (int gg = 0; gg < 3; gg++){
                const int gidx = wave + gg*8;
                const int h = gidx >> 1, cg = gidx & 1;
                const int chL = h*HD + cg*32 + mB;     // logical chan for B
                f32x16 acc = accB32[gg];
                #pragma unroll
                for (int k0 = 0; k0 < 64; k0 += 16){
                    const int kbase = k0 + halfB*8;
                    // A: dS[mB][kbase .. +8]  (swizzle-compatible contiguous)
                    bf16x8 a = *(const bf16x8*)&dsbuf[h][mB][kbase ^ ((mB & 7) << 3)];
                    // B: colmat[kbase+jj][chL], jj=0..7 ; swizzle const over jj
                    const int sw = ((kbase >> 3) & 3) << 3;
                    const unsigned short* bp = &colbuf[kbase][chL ^ sw];
                    bf16x8 b;
                    #pragma unroll
                    for (int jj = 0; jj < 8; jj++)
                        b[jj] = (short)bp[jj * CBS];
                    acc = __builtin_amdgcn_mfma_f32_32x32x16_bf16(a, b, acc, 0, 0, 0);
                }
                accB32[gg] = acc;
            }
        }
    }
    // ---- write dRow partials (32x32 D layout, r5-verified) ----
    float* outp = out_part + (size_t)blockIdx.y * N_TOK * CDIM;
    #pragma unroll
    for (int gg = 0; gg < 3; gg++){
        const int gidx = wave + gg*8;
        const int h = gidx >> 1, cg = gidx & 1;
        #pragma unroll
        for (int q = 0; q < 16; q++){
            const int i = (q & 3) + 8*(q >> 2) + 4*(lane >> 5);
            outp[(size_t)(rt0 + i) * CDIM + h*HD + cg*32 + (lane & 31)] = accB32[gg][q];
        }
    }
}

// ---------------------------------------------------------------------------
// final (r11-verbatim): templated NSEG + register prefetch.
// ---------------------------------------------------------------------------
template<int NSEG>
__global__ __launch_bounds__(256) void final_dg_kernel(
    const float* __restrict__ dQbp, const float* __restrict__ dKhp,
    const float* __restrict__ Wq, const float* __restrict__ Wk,
    const float* __restrict__ betas, float* __restrict__ dg)
{
    __shared__ float at[16][68];
    __shared__ float bt[16][68];
    const int n0 = blockIdx.x * 64, d0 = blockIdx.y * 64;
    const int t  = threadIdx.x;
    const int tx = t & 15, ty = t >> 4;
    const int lr = t >> 2, lk = (t & 3) * 4;
    const int wk = t >> 4, wd = (t & 15) * 4;   // W staging mapping
    float acc[4][4] = {};

    f32x4 la[NSEG];
    f32x4 lw;
    auto issue = [&](int it){
        const int src = it / 48;
        const int c0i = (it % 48) * 16;
        const float* P = src ? dKhp : dQbp;
        const float* W = src ? Wk  : Wq;
        #pragma unroll
        for (int s = 0; s < NSEG; s++)
            la[s] = *(const f32x4*)&P[((size_t)s * N_TOK + n0 + lr) * CDIM + c0i + lk];
        lw = *(const f32x4*)&W[(size_t)(c0i + wk) * DIM_IN + d0 + wd];
    };
    issue(0);

    for (int it = 0; it < 96; it++){
        const int src = it / 48;
        const int c0i = (it % 48) * 16;
        __syncthreads();
        f32x4 a = la[0];
        #pragma unroll
        for (int s = 1; s < NSEG; s++) a += la[s];
        if (src == 0) a *= betas[(c0i + lk) >> 6];
        at[lk+0][lr] = a[0]; at[lk+1][lr] = a[1]; at[lk+2][lr] = a[2]; at[lk+3][lr] = a[3];
        bt[wk][wd+0] = lw[0]; bt[wk][wd+1] = lw[1]; bt[wk][wd+2] = lw[2]; bt[wk][wd+3] = lw[3];
        __syncthreads();
        issue(it + 1 < 96 ? it + 1 : 0);   // clamped dummy on last iter
        #pragma unroll
        for (int kk = 0; kk < 16; kk++){
            f32x4 av = *(const f32x4*)&at[kk][ty*4];
            f32x4 bv = *(const f32x4*)&bt[kk][tx*4];
            #pragma unroll
            for (int i = 0; i < 4; i++)
                #pragma unroll
                for (int j = 0; j < 4; j++)
                    acc[i][j] += av[i] * bv[j];
        }
    }
    #pragma unroll
    for (int i = 0; i < 4; i++)
        #pragma unroll
        for (int j = 0; j < 4; j++)
            dg[(size_t)(n0 + ty*4 + i) * DIM_IN + d0 + tx*4 + j] = acc[i][j];
}

// ---------------------------------------------------------------------------
extern "C" void kernel_launch(void* const* d_in, const int* in_sizes, int n_in,
                              void* d_out, int out_size, void* d_ws, size_t ws_size,
                              hipStream_t stream)
{
    const float* g     = (const float*)d_in[0];
    const float* adj   = (const float*)d_in[1];
    const float* Wk    = (const float*)d_in[2];
    const float* Wq    = (const float*)d_in[3];
    const float* Hw    = (const float*)d_in[4];
    const float* Bk    = (const float*)d_in[5];
    const float* Bq    = (const float*)d_in[6];
    const float* betas = (const float*)d_in[7];
    float* out = (float*)d_out;

    char* ws = (char*)d_ws;
    const size_t szQb   = (size_t)N_TOK * CDIM * sizeof(unsigned short); // 6291456
    const size_t szL    = (size_t)N_TOK * NH * sizeof(float);            // 196608
    const size_t szPart = (size_t)N_TOK * CDIM * sizeof(float);          // 12582912

    unsigned short* Qb = (unsigned short*)(ws);
    unsigned short* Kh = (unsigned short*)(ws + szQb);
    float* l_ws   = (float*)(ws + 2*szQb);
    float* lse_ws = (float*)(ws + 2*szQb + szL);
    char*  parts  = ws + 2*szQb + 2*szL;
    const size_t base = 2*szQb + 2*szL;

    int KS = 1;
    if      (ws_size >= base + 8*szPart) KS = 4;
    else if (ws_size >= base + 4*szPart) KS = 2;
    float* dQbp = (float*)parts;
    float* dKhp = (float*)(parts + (size_t)KS * szPart);

    hipMemsetAsync(l_ws, 0, szL, stream);
    hipMemsetAsync(d_out, 0, sizeof(float), stream);

    proj_kernel<<<dim3(64, 12, 2), 256, 0, stream>>>(g, Wq, Wk, Bq, Bk, betas, Qb, Kh);
    fwd_kernel<<<dim3(64, 8), 256, 0, stream>>>(Qb, Kh, adj, Hw, l_ws, N_TOK / 8);
    lse_energy_kernel<<<dim3(192), 256, 0, stream>>>(l_ws, lse_ws, betas, out);
    bwd_kernel<0><<<dim3(128, KS), 512, 0, stream>>>(Qb, Kh, adj, Hw, lse_ws, betas,
                                                     dQbp, N_TOK / KS);
    bwd_kernel<1><<<dim3(128, KS), 512, 0, stream>>>(Kh, Qb, adj, Hw, lse_ws, betas,
                                                     dKhp, N_TOK / KS);
    if (KS == 4)
        final_dg_kernel<4><<<dim3(64, 8), 256, 0, stream>>>(dQbp, dKhp, Wq, Wk, betas, out + 1);
    else if (KS == 2)
        final_dg_kernel<2><<<dim3(64, 8), 256, 0, stream>>>(dQbp, dKhp, Wq, Wk, betas, out + 1);
    else
        final_dg_kernel<1><<<dim3(64, 8), 256, 0, stream>>>(dQbp, dKhp, Wq, Wk, betas, out + 1);
}

// Round 14
// 1367.430 us; speedup vs baseline: 1.1289x; 1.0086x over previous
//
#include <hip/hip_runtime.h>
#include <stdint.h>

#define N_TOK 4096
#define DIM_IN 512
#define NH 12
#define HD 64
#define CDIM 768   // NH*HD

using f32x4  = __attribute__((ext_vector_type(4))) float;
using f32x16 = __attribute__((ext_vector_type(16))) float;
using bf16x8 = __attribute__((ext_vector_type(8))) short;

static __device__ __forceinline__ unsigned short f2bf(float f){
    union { float f; unsigned int u; } v; v.f = f;
    unsigned int r = v.u + 0x7fffu + ((v.u >> 16) & 1u);
    return (unsigned short)(r >> 16);
}

// ---------------------------------------------------------------------------
// proj (r13-verified): both projections in ONE launch (blockIdx.z selects
// Wq/Wk); register prefetch of next d0-tile.
// ---------------------------------------------------------------------------
__global__ __launch_bounds__(256) void proj_kernel(
    const float* __restrict__ g,
    const float* __restrict__ Wq, const float* __restrict__ Wk,
    const float* __restrict__ Bq, const float* __restrict__ Bk,
    const float* __restrict__ betas,
    unsigned short* __restrict__ Qb, unsigned short* __restrict__ Kh)
{
    const int z = blockIdx.z;
    const float* W = z ? Wk : Wq;
    const float* B = z ? Bk : Bq;
    const float* scale = z ? nullptr : betas;
    unsigned short* out = z ? Kh : Qb;

    __shared__ float at[16][68];
    __shared__ float bt[16][68];
    const int n0 = blockIdx.x * 64, c0 = blockIdx.y * 64;
    const int t  = threadIdx.x;
    const int tx = t & 15, ty = t >> 4;
    const int lr = t >> 2, lk = (t & 3) * 4;
    float acc[4][4] = {};
    f32x4 pg = *(const f32x4*)&g[(size_t)(n0 + lr) * DIM_IN + lk];
    f32x4 pw = *(const f32x4*)&W[(size_t)(c0 + lr) * DIM_IN + lk];
    for (int d0 = 0; d0 < DIM_IN; d0 += 16){
        __syncthreads();
        at[lk+0][lr] = pg[0]; at[lk+1][lr] = pg[1]; at[lk+2][lr] = pg[2]; at[lk+3][lr] = pg[3];
        bt[lk+0][lr] = pw[0]; bt[lk+1][lr] = pw[1]; bt[lk+2][lr] = pw[2]; bt[lk+3][lr] = pw[3];
        __syncthreads();
        {
            const int dn = (d0 + 16 < DIM_IN) ? d0 + 16 : 0;   // clamped dummy
            pg = *(const f32x4*)&g[(size_t)(n0 + lr) * DIM_IN + dn + lk];
            pw = *(const f32x4*)&W[(size_t)(c0 + lr) * DIM_IN + dn + lk];
        }
        #pragma unroll
        for (int kk = 0; kk < 16; kk++){
            f32x4 av = *(const f32x4*)&at[kk][ty*4];
            f32x4 bv = *(const f32x4*)&bt[kk][tx*4];
            #pragma unroll
            for (int i = 0; i < 4; i++)
                #pragma unroll
                for (int j = 0; j < 4; j++)
                    acc[i][j] += av[i] * bv[j];
        }
    }
    #pragma unroll
    for (int i = 0; i < 4; i++){
        const int n = n0 + ty*4 + i;
        #pragma unroll
        for (int j = 0; j < 4; j++){
            const int c = c0 + tx*4 + j;
            float v = acc[i][j] + B[c];
            if (scale) v *= scale[c >> 6];
            out[(size_t)n * CDIM + c] = f2bf(v);
        }
    }
}

// ---------------------------------------------------------------------------
// forward (r11-verbatim, verified): kbuf staging + pk[12] register prefetch
// issued after the post-staging barrier; af reloaded per sub via laundered
// pointer so demand stays ~185 <= 256 with pk live through compute.
// ---------------------------------------------------------------------------
#define TKF 32
#define KBS 776   // ushort stride: 1552 B (16B aligned, 2-way-bank only)

__global__ __launch_bounds__(256, 2) void fwd_kernel(
    const unsigned short* __restrict__ Qb, const unsigned short* __restrict__ Kh,
    const float* __restrict__ adj, const float* __restrict__ HwG,
    float* __restrict__ l_ws, int seg_len)
{
    __shared__ unsigned short kbuf[TKF][KBS];
    __shared__ float hw[NH][12];
    const int t = threadIdx.x;
    if (t < NH * 12) hw[t / 12][t % 12] = HwG[t];
    const int lane = t & 63, wave = t >> 6;
    const int quad = lane >> 4, col = lane & 15;
    const int qt0 = blockIdx.x * 64 + wave * 16;
    const int kstart = blockIdx.y * seg_len;
    const unsigned short* qrow = &Qb[(size_t)(qt0 + col) * CDIM + quad*8];

    f32x4 l4[4][3];
    #pragma unroll
    for (int r = 0; r < 4; r++)
        #pragma unroll
        for (int j = 0; j < 3; j++)
            l4[r][j] = (f32x4){0.f,0.f,0.f,0.f};

    // ---- prologue prefetch (chunk 0) ----
    bf16x8 pk[12];
    #pragma unroll
    for (int i = 0; i < 12; i++){
        const int idx = t + 256 * i;
        const int row = idx / 96, cc = (idx % 96) * 8;
        pk[i] = *(const bf16x8*)&Kh[(size_t)(kstart + row) * CDIM + cc];
    }

    for (int kc = kstart; kc < kstart + seg_len; kc += TKF){
        __syncthreads();
        #pragma unroll
        for (int i = 0; i < 12; i++){
            const int idx = t + 256 * i;
            const int row = idx / 96, cc = (idx % 96) * 8;
            *(bf16x8*)&kbuf[row][cc] = pk[i];
        }
        __syncthreads();

        // issue next chunk's loads: covered by the full 2-sub compute below
        {
            const int nxt = kc + TKF;
            const int kcn = (nxt < kstart + seg_len) ? nxt : kstart;  // clamped dummy
            #pragma unroll
            for (int i = 0; i < 12; i++){
                const int idx = t + 256 * i;
                const int row = idx / 96, cc = (idx % 96) * 8;
                pk[i] = *(const bf16x8*)&Kh[(size_t)(kcn + row) * CDIM + cc];
            }
        }

        #pragma unroll
        for (int sub = 0; sub < 2; sub++){
            const int k0 = kc + sub * 16;
            float av[4];
            #pragma unroll
            for (int r = 0; r < 4; r++)
                av[r] = adj[(size_t)(qt0 + quad*4 + r) * N_TOK + k0 + col];

            const unsigned short* qp = qrow;
            asm volatile("" : "+v"(qp));

            f32x4 tv[4][3];
            #pragma unroll
            for (int r = 0; r < 4; r++)
                #pragma unroll
                for (int j = 0; j < 3; j++)
                    tv[r][j] = (f32x4){0.f,0.f,0.f,0.f};
            #pragma unroll
            for (int h = 0; h < NH; h++){
                bf16x8 a0 = *(const bf16x8*)&qp[h*HD];
                bf16x8 a1 = *(const bf16x8*)&qp[h*HD + 32];
                bf16x8 b0 = *(const bf16x8*)&kbuf[sub*16 + col][h*HD + quad*8];
                bf16x8 b1 = *(const bf16x8*)&kbuf[sub*16 + col][h*HD + 32 + quad*8];
                f32x4 s = {0.f,0.f,0.f,0.f};
                s = __builtin_amdgcn_mfma_f32_16x16x32_bf16(a0, b0, s, 0, 0, 0);
                s = __builtin_amdgcn_mfma_f32_16x16x32_bf16(a1, b1, s, 0, 0, 0);
                f32x4 w0 = *(const f32x4*)&hw[h][0];
                f32x4 w1 = *(const f32x4*)&hw[h][4];
                f32x4 w2 = *(const f32x4*)&hw[h][8];
                #pragma unroll
                for (int r = 0; r < 4; r++){
                    tv[r][0] += s[r] * w0;
                    tv[r][1] += s[r] * w1;
                    tv[r][2] += s[r] * w2;
                }
            }
            #pragma unroll
            for (int r = 0; r < 4; r++){
                #pragma unroll
                for (int j = 0; j < 3; j++){
                    #pragma unroll
                    for (int c = 0; c < 4; c++){
                        const float mm = tv[r][j][c] * av[r];   // matches T*adj
                        if (mm != 0.f) l4[r][j][c] += __expf(mm);
                    }
                }
            }
        }
    }
    #pragma unroll
    for (int r = 0; r < 4; r++)
        #pragma unroll
        for (int j = 0; j < 3; j++)
            #pragma unroll
            for (int c = 0; c < 4; c++){
                float v = l4[r][j][c];
                v += __shfl_xor(v, 1, 16);
                v += __shfl_xor(v, 2, 16);
                v += __shfl_xor(v, 4, 16);
                v += __shfl_xor(v, 8, 16);
                if (col == j*4 + c)
                    atomicAdd(&l_ws[(size_t)(qt0 + quad*4 + r) * NH + (j*4 + c)], v);
            }
}

// ---------------------------------------------------------------------------
// lse + energy
// ---------------------------------------------------------------------------
__global__ __launch_bounds__(256) void lse_energy_kernel(
    const float* __restrict__ l_ws, float* __restrict__ lse_ws,
    const float* __restrict__ betas, float* __restrict__ energy)
{
    const int t = threadIdx.x;
    const int i = blockIdx.x * 256 + t;
    const float l = l_ws[i];
    float lse, ep;
    if (l > 0.f){ lse = logf(l); ep = -(1.f / betas[i % NH]) * lse; }
    else        { lse = -1e30f; ep = 0.f; }
    lse_ws[i] = lse;
    __shared__ float red[256];
    red[t] = ep;
    __syncthreads();
    for (int s = 128; s > 0; s >>= 1){
        if (t < s) red[t] += red[t + s];
        __syncthreads();
    }
    if (t == 0) atomicAdd(energy, red[0]);
}

// ---------------------------------------------------------------------------
// backward: r11-VERBATIM (FROZEN at its structural floor, ~480-505us).
// Constraint ledger: 2 waves/EU -> 256-reg cap, demand ~170; r6 (global
// operands), r7 (colmatT), r8 (early prefetch), r12 (gload_lds analog)
// all regressed.  FETCH ~98MB is near-ideal (adj read-once dominates).
// seg_len is a runtime arg: KS change below does NOT touch this codegen.
// ---------------------------------------------------------------------------
#define CBS 776   // colbuf ushort stride

template<int MODE>
__global__ __attribute__((amdgpu_flat_work_group_size(512, 512), amdgpu_waves_per_eu(2, 2)))
void bwd_kernel(
    const unsigned short* __restrict__ rowmat, const unsigned short* __restrict__ colmat,
    const float* __restrict__ adj, const float* __restrict__ HwG,
    const float* __restrict__ lse_ws, const float* __restrict__ betas,
    float* __restrict__ out_part, int seg_len)
{
    __shared__ unsigned short colbuf[64][CBS];     // 99328 B
    __shared__ unsigned short dsbuf[NH][32][64];   // 49152 B
    __shared__ float adjbuf[32][68];               //  8704 B
    __shared__ float lsebuf[64 * NH];              //  3072 B (mode 1 only)
    __shared__ float rowlse[32 * NH];              //  1536 B (mode 0 only)
    __shared__ float invbuf[NH];                   //    48 B
    __shared__ float hw[NH][12];                   //   576 B
    const int t = threadIdx.x;
    if (t < NH * 12) hw[t / 12][t % 12] = HwG[t];
    if (t < NH) invbuf[t] = 1.f / betas[t];
    const int lane = t & 63, wave = t >> 6;
    const int quad = lane >> 4, col = lane & 15;
    const int rsub = wave >> 2, csub = wave & 3;
    const int n0 = csub * 16;
    const int rt0 = blockIdx.x * 32;
    const int rbase = rt0 + rsub * 16;       // this wave's 16 rows (phase A)
    const int cstart = blockIdx.y * seg_len;
    const int tA = n0 + col;

    if (MODE == 0 && t < 96)
        *(f32x4*)&rowlse[t*4] = *(const f32x4*)&lse_ws[(size_t)rt0 * NH + t*4];

    // A-fragment source row for this lane (16 B aligned vector loads)
    const unsigned short* rowp = &rowmat[(size_t)(rbase + col) * CDIM + quad*8];

    const int adj_m  = t >> 4, adj_nc = (t & 15) * 4;   // mode 0
    const int adj_qr = t >> 3, adj_kc = (t & 7) * 4;    // mode 1

    // ---- initial prefetch (chunk 0) ----
    bf16x8 pcol[12];
    f32x4  padj;
    f32x4  plse = {0.f,0.f,0.f,0.f};
    {
        const int cb = cstart;
        #pragma unroll
        for (int i = 0; i < 12; i++){
            const int idx = t + 512 * i;
            const int row = idx / 96, cc = (idx % 96) * 8;
            pcol[i] = *(const bf16x8*)&colmat[(size_t)(cb + row) * CDIM + cc];
        }
        if (MODE == 0) padj = *(const f32x4*)&adj[(size_t)(rt0 + adj_m) * N_TOK + cb + adj_nc];
        else           padj = *(const f32x4*)&adj[(size_t)(cb + adj_qr) * N_TOK + rt0 + adj_kc];
        if (MODE == 1 && t < 192)
            plse = *(const f32x4*)&lse_ws[(size_t)cb * NH + t*4];
    }

    f32x16 accB32[3];
    #pragma unroll
    for (int gg = 0; gg < 3; gg++)
        #pragma unroll
        for (int q = 0; q < 16; q++) accB32[gg][q] = 0.f;

    for (int cb = cstart; cb < cstart + seg_len; cb += 64){
        __syncthreads();
        // ---- write prefetched chunk into LDS ----
        #pragma unroll
        for (int i = 0; i < 12; i++){
            const int idx = t + 512 * i;
            const int row = idx / 96, cc = (idx % 96) * 8;
            // swizzled store: logical channel c lives at c ^ ((row>>3 & 3)<<3)
            *(bf16x8*)&colbuf[row][cc ^ (((row >> 3) & 3) << 3)] = pcol[i];
        }
        if (MODE == 0){
            adjbuf[adj_m][adj_nc+0] = padj[0]; adjbuf[adj_m][adj_nc+1] = padj[1];
            adjbuf[adj_m][adj_nc+2] = padj[2]; adjbuf[adj_m][adj_nc+3] = padj[3];
        } else {
            adjbuf[adj_kc+0][adj_qr] = padj[0]; adjbuf[adj_kc+1][adj_qr] = padj[1];
            adjbuf[adj_kc+2][adj_qr] = padj[2]; adjbuf[adj_kc+3][adj_qr] = padj[3];
        }
        if (MODE == 1 && t < 192)
            *(f32x4*)&lsebuf[t*4] = plse;
        __syncthreads();

        // launder the A-row pointer so the per-h loads below cannot be
        // hoisted out of the cb loop (would recreate a 96-reg af array)
        const unsigned short* rp = rowp;
        asm volatile("" : "+v"(rp));

        // ---- phase A: this wave's 16 rows x 16 cols (csub subtile) ----
        {
            const int swzA = ((tA >> 3) & 3) << 3;
            f32x4 G[4][3];
            #pragma unroll
            for (int r = 0; r < 4; r++)
                #pragma unroll
                for (int j = 0; j < 3; j++)
                    G[r][j] = (f32x4){0.f,0.f,0.f,0.f};
            #pragma unroll
            for (int h = 0; h < NH; h++){
                bf16x8 a0 = *(const bf16x8*)&rp[h*HD];
                bf16x8 a1 = *(const bf16x8*)&rp[h*HD + 32];
                bf16x8 b0 = *(const bf16x8*)&colbuf[tA][(h*HD + quad*8) ^ swzA];
                bf16x8 b1 = *(const bf16x8*)&colbuf[tA][(h*HD + 32 + quad*8) ^ swzA];
                f32x4 s = {0.f,0.f,0.f,0.f};
                s = __builtin_amdgcn_mfma_f32_16x16x32_bf16(a0, b0, s, 0, 0, 0);
                s = __builtin_amdgcn_mfma_f32_16x16x32_bf16(a1, b1, s, 0, 0, 0);
                f32x4 w0 = *(const f32x4*)&hw[h][0];
                f32x4 w1 = *(const f32x4*)&hw[h][4];
                f32x4 w2 = *(const f32x4*)&hw[h][8];
                #pragma unroll
                for (int r = 0; r < 4; r++){
                    G[r][0] += s[r] * w0;
                    G[r][1] += s[r] * w1;
                    G[r][2] += s[r] * w2;
                }
            }
            // t-values -> gradient G = -(1/b')*P   (lse + 1/beta from LDS)
            #pragma unroll
            for (int r = 0; r < 4; r++){
                const float adjv = adjbuf[rsub*16 + quad*4 + r][tA];
                #pragma unroll
                for (int j = 0; j < 3; j++){
                    f32x4 lv;
                    if (MODE == 0) lv = *(const f32x4*)&rowlse[(rsub*16 + quad*4 + r) * NH + j*4];
                    else           lv = *(const f32x4*)&lsebuf[tA * NH + j*4];
                    #pragma unroll
                    for (int c = 0; c < 4; c++){
                        const float mm = G[r][j][c] * adjv;
                        const float p  = (mm != 0.f) ? __expf(mm - lv[c]) : 0.f;
                        G[r][j][c] = -invbuf[j*4 + c] * p;
                    }
                }
            }
            // dS = G @ Hw^T, bf16 into dsbuf (swizzled: kk' = kk ^ ((m&7)<<3))
            #pragma unroll
            for (int h = 0; h < NH; h++){
                f32x4 w0 = *(const f32x4*)&hw[h][0];
                f32x4 w1 = *(const f32x4*)&hw[h][4];
                f32x4 w2 = *(const f32x4*)&hw[h][8];
                #pragma unroll
                for (int r = 0; r < 4; r++){
                    f32x4 pr = G[r][0]*w0 + G[r][1]*w1 + G[r][2]*w2;
                    const float d = pr[0] + pr[1] + pr[2] + pr[3];
                    const int m = rsub*16 + quad*4 + r;
                    dsbuf[h][m][tA ^ ((m & 7) << 3)] = f2bf(d);
                }
            }
        }

        // ---- issue prefetch of chunk t+1 (G dead; r5/r9 placement) ----
        {
            const int nxt = cb + 64;
            const int cbn = (nxt < cstart + seg_len) ? nxt : cstart;  // clamp (discarded)
            #pragma unroll
            for (int i = 0; i < 12; i++){
                const int idx = t + 512 * i;
                const int row = idx / 96, cc = (idx % 96) * 8;
                pcol[i] = *(const bf16x8*)&colmat[(size_t)(cbn + row) * CDIM + cc];
            }
            if (MODE == 0) padj = *(const f32x4*)&adj[(size_t)(rt0 + adj_m) * N_TOK + cbn + adj_nc];
            else           padj = *(const f32x4*)&adj[(size_t)(cbn + adj_qr) * N_TOK + rt0 + adj_kc];
            if (MODE == 1 && t < 192)
                plse = *(const f32x4*)&lse_ws[(size_t)cbn * NH + t*4];
        }
        __syncthreads();

        // ---- phase B (32x32x16): dRow[m][z] += sum_kk dS[m][kk]*colmat[kk][z]
        {
            const int mB = lane & 31;
            const int halfB = lane >> 5;
            #pragma unroll
            for (int gg = 0; gg < 3; gg++){
                const int gidx = wave + gg*8;
                const int h = gidx >> 1, cg = gidx & 1;
                const int chL = h*HD + cg*32 + mB;     // logical chan for B
                f32x16 acc = accB32[gg];
                #pragma unroll
                for (int k0 = 0; k0 < 64; k0 += 16){
                    const int kbase = k0 + halfB*8;
                    // A: dS[mB][kbase .. +8]  (swizzle-compatible contiguous)
                    bf16x8 a = *(const bf16x8*)&dsbuf[h][mB][kbase ^ ((mB & 7) << 3)];
                    // B: colmat[kbase+jj][chL], jj=0..7 ; swizzle const over jj
                    const int sw = ((kbase >> 3) & 3) << 3;
                    const unsigned short* bp = &colbuf[kbase][chL ^ sw];
                    bf16x8 b;
                    #pragma unroll
                    for (int jj = 0; jj < 8; jj++)
                        b[jj] = (short)bp[jj * CBS];
                    acc = __builtin_amdgcn_mfma_f32_32x32x16_bf16(a, b, acc, 0, 0, 0);
                }
                accB32[gg] = acc;
            }
        }
    }
    // ---- write dRow partials (32x32 D layout, r5-verified) ----
    float* outp = out_part + (size_t)blockIdx.y * N_TOK * CDIM;
    #pragma unroll
    for (int gg = 0; gg < 3; gg++){
        const int gidx = wave + gg*8;
        const int h = gidx >> 1, cg = gidx & 1;
        #pragma unroll
        for (int q = 0; q < 16; q++){
            const int i = (q & 3) + 8*(q >> 2) + 4*(lane >> 5);
            outp[(size_t)(rt0 + i) * CDIM + h*HD + cg*32 + (lane & 31)] = accB32[gg][q];
        }
    }
}

// ---------------------------------------------------------------------------
// final (r11-verified): templated NSEG + register prefetch.  Only NSEG=2/1
// instantiated now (KS capped at 2): halves partial-read traffic vs KS=4
// and trims co-compiled code.
// ---------------------------------------------------------------------------
template<int NSEG>
__global__ __launch_bounds__(256) void final_dg_kernel(
    const float* __restrict__ dQbp, const float* __restrict__ dKhp,
    const float* __restrict__ Wq, const float* __restrict__ Wk,
    const float* __restrict__ betas, float* __restrict__ dg)
{
    __shared__ float at[16][68];
    __shared__ float bt[16][68];
    const int n0 = blockIdx.x * 64, d0 = blockIdx.y * 64;
    const int t  = threadIdx.x;
    const int tx = t & 15, ty = t >> 4;
    const int lr = t >> 2, lk = (t & 3) * 4;
    const int wk = t >> 4, wd = (t & 15) * 4;   // W staging mapping
    float acc[4][4] = {};

    f32x4 la[NSEG];
    f32x4 lw;
    auto issue = [&](int it){
        const int src = it / 48;
        const int c0i = (it % 48) * 16;
        const float* P = src ? dKhp : dQbp;
        const float* W = src ? Wk  : Wq;
        #pragma unroll
        for (int s = 0; s < NSEG; s++)
            la[s] = *(const f32x4*)&P[((size_t)s * N_TOK + n0 + lr) * CDIM + c0i + lk];
        lw = *(const f32x4*)&W[(size_t)(c0i + wk) * DIM_IN + d0 + wd];
    };
    issue(0);

    for (int it = 0; it < 96; it++){
        const int src = it / 48;
        const int c0i = (it % 48) * 16;
        __syncthreads();
        f32x4 a = la[0];
        #pragma unroll
        for (int s = 1; s < NSEG; s++) a += la[s];
        if (src == 0) a *= betas[(c0i + lk) >> 6];
        at[lk+0][lr] = a[0]; at[lk+1][lr] = a[1]; at[lk+2][lr] = a[2]; at[lk+3][lr] = a[3];
        bt[wk][wd+0] = lw[0]; bt[wk][wd+1] = lw[1]; bt[wk][wd+2] = lw[2]; bt[wk][wd+3] = lw[3];
        __syncthreads();
        issue(it + 1 < 96 ? it + 1 : 0);   // clamped dummy on last iter
        #pragma unroll
        for (int kk = 0; kk < 16; kk++){
            f32x4 av = *(const f32x4*)&at[kk][ty*4];
            f32x4 bv = *(const f32x4*)&bt[kk][tx*4];
            #pragma unroll
            for (int i = 0; i < 4; i++)
                #pragma unroll
                for (int j = 0; j < 4; j++)
                    acc[i][j] += av[i] * bv[j];
        }
    }
    #pragma unroll
    for (int i = 0; i < 4; i++)
        #pragma unroll
        for (int j = 0; j < 4; j++)
            dg[(size_t)(n0 + ty*4 + i) * DIM_IN + d0 + tx*4 + j] = acc[i][j];
}

// ---------------------------------------------------------------------------
extern "C" void kernel_launch(void* const* d_in, const int* in_sizes, int n_in,
                              void* d_out, int out_size, void* d_ws, size_t ws_size,
                              hipStream_t stream)
{
    const float* g     = (const float*)d_in[0];
    const float* adj   = (const float*)d_in[1];
    const float* Wk    = (const float*)d_in[2];
    const float* Wq    = (const float*)d_in[3];
    const float* Hw    = (const float*)d_in[4];
    const float* Bk    = (const float*)d_in[5];
    const float* Bq    = (const float*)d_in[6];
    const float* betas = (const float*)d_in[7];
    float* out = (float*)d_out;

    char* ws = (char*)d_ws;
    const size_t szQb   = (size_t)N_TOK * CDIM * sizeof(unsigned short); // 6291456
    const size_t szL    = (size_t)N_TOK * NH * sizeof(float);            // 196608
    const size_t szPart = (size_t)N_TOK * CDIM * sizeof(float);          // 12582912

    unsigned short* Qb = (unsigned short*)(ws);
    unsigned short* Kh = (unsigned short*)(ws + szQb);
    float* l_ws   = (float*)(ws + 2*szQb);
    float* lse_ws = (float*)(ws + 2*szQb + szL);
    char*  parts  = ws + 2*szQb + 2*szL;
    const size_t base = 2*szQb + 2*szL;

    // KS capped at 2 (was 4): bwd wall is work/CU-identical (256 blocks =
    // exactly 1/CU in one scheduling round vs 512 in two), prologue amortizes
    // over 2x chunks, and final_dg's partial-read traffic HALVES (8 -> 4
    // partial sets).  bwd kernel codegen untouched (seg_len is runtime).
    int KS = (ws_size >= base + 4*szPart) ? 2 : 1;
    float* dQbp = (float*)parts;
    float* dKhp = (float*)(parts + (size_t)KS * szPart);

    hipMemsetAsync(l_ws, 0, szL, stream);
    hipMemsetAsync(d_out, 0, sizeof(float), stream);

    proj_kernel<<<dim3(64, 12, 2), 256, 0, stream>>>(g, Wq, Wk, Bq, Bk, betas, Qb, Kh);
    fwd_kernel<<<dim3(64, 8), 256, 0, stream>>>(Qb, Kh, adj, Hw, l_ws, N_TOK / 8);
    lse_energy_kernel<<<dim3(192), 256, 0, stream>>>(l_ws, lse_ws, betas, out);
    bwd_kernel<0><<<dim3(128, KS), 512, 0, stream>>>(Qb, Kh, adj, Hw, lse_ws, betas,
                                                     dQbp, N_TOK / KS);
    bwd_kernel<1><<<dim3(128, KS), 512, 0, stream>>>(Kh, Qb, adj, Hw, lse_ws, betas,
                                                     dKhp, N_TOK / KS);
    if (KS == 2)
        final_dg_kernel<2><<<dim3(64, 8), 256, 0, stream>>>(dQbp, dKhp, Wq, Wk, betas, out + 1);
    else
        final_dg_kernel<1><<<dim3(64, 8), 256, 0, stream>>>(dQbp, dKhp, Wq, Wk, betas, out + 1);
}